// Round 4
// baseline (404.623 us; speedup 1.0000x reference)
//
#include <hip/hip_runtime.h>
#include <math.h>

#define FF 64
#define FP1 65
#define BB 32
#define LL 128
#define NBL 4096        // BB*LL
#define NIJ 4096        // FF*FF

// ---- ws layout (bytes) ----
#define OFF_SLABJ 0ull              // slabJ[j][i][m]: 64*64*64*4 = 1,048,576
#define OFF_FLAG  1048576ull        // 4 B
#define WS_NEED   1048640ull

// ============ stage 1: slabJ[j][i][m] = inter[i][j][m][0]; zero flag ============
__global__ void build_slabJ(const float* __restrict__ inter, float* __restrict__ slabJ,
                            int* __restrict__ flag) {
    int t = blockIdx.x * blockDim.x + threadIdx.x;
    if (t == 0 && flag) *flag = 0;
    if (t < FF * FF * FF) {
        int m = t & 63;
        int i = (t >> 6) & 63;
        int j = t >> 12;
        slabJ[t] = inter[((size_t)((i << 6) + j) * FF + m) * FP1];
    }
}

// old layout kept only for the small-ws fallback path
__global__ void build_slab0(const float* __restrict__ inter, float* __restrict__ slab0T) {
    int t = blockIdx.x * blockDim.x + threadIdx.x;
    if (t < FF * FF * FF) {
        int m = t >> 12;
        int ij = t & 4095;
        slab0T[t] = inter[((size_t)ij * FF + m) * FP1];
    }
}

// ============ stage 2: fused D0 + col-softmax + matvec, no D0 materialization ============
// grid (32 b, 16 lt), block 256 (4 waves). Block owns 8 l-rows; wave owns 16 j-cols.
// lane = i. acc[lq] = D0[b,l0+lq, i*64+j] computed from reg-held slab slice + LDS x.

#define COMPUTE_J(SR, J)                                                          \
    do {                                                                          \
        const int j_ = (J);                                                       \
        float acc[8];                                                             \
        _Pragma("unroll")                                                         \
        for (int q_ = 0; q_ < 8; ++q_) acc[q_] = 0.f;                             \
        _Pragma("unroll")                                                         \
        for (int q_ = 0; q_ < 16; ++q_) {                                         \
            _Pragma("unroll")                                                     \
            for (int mi_ = 0; mi_ < 4; ++mi_) {                                   \
                const int m_ = q_ * 4 + mi_;                                      \
                const float sv_ = ((const float*)&SR[q_])[mi_];                   \
                const float4 xa_ = *(const float4*)&xT[m_][0];                    \
                const float4 xb_ = *(const float4*)&xT[m_][4];                    \
                acc[0] += sv_ * xa_.x; acc[1] += sv_ * xa_.y;                     \
                acc[2] += sv_ * xa_.z; acc[3] += sv_ * xa_.w;                     \
                acc[4] += sv_ * xb_.x; acc[5] += sv_ * xb_.y;                     \
                acc[6] += sv_ * xb_.z; acc[7] += sv_ * xb_.w;                     \
            }                                                                     \
        }                                                                         \
        _Pragma("unroll")                                                         \
        for (int lq_ = 0; lq_ < 8; ++lq_) {                                       \
            float z_ = 7.0f * acc[lq_];                                           \
            mn = fminf(mn, z_);                                                   \
            float mx_ = z_;                                                       \
            _Pragma("unroll")                                                     \
            for (int o_ = 32; o_; o_ >>= 1) mx_ = fmaxf(mx_, __shfl_xor(mx_, o_));\
            float e_ = expf(z_ - mx_);                                            \
            float sm_ = e_;                                                       \
            _Pragma("unroll")                                                     \
            for (int o_ = 32; o_; o_ >>= 1) sm_ += __shfl_xor(sm_, o_);           \
            const float w_ = e_ * (1.0f / sm_);                                   \
            racc[lq_] += w_ * xT[j_][lq_];                                        \
            if (lt == 15 && lq_ == 7)                                             \
                out[(size_t)BB * LL * FF + (size_t)b * NIJ + lane * 64 + j_] = w_;\
        }                                                                         \
    } while (0)

__launch_bounds__(256)
__global__ void fused_scan(const float* __restrict__ x,
                           const float* __restrict__ slabJ,
                           float* __restrict__ out,
                           int* __restrict__ flag) {
    __shared__ __align__(16) float xT[FF][12];     // [m][lq], rows 48B (16B-aligned)
    __shared__ __align__(16) float part[4][8][FF]; // 8 KB
    __shared__ float mnred[4];

    const int b = blockIdx.x, lt = blockIdx.y;
    const int l0 = lt * 8;
    const int tid = threadIdx.x, wave = tid >> 6, lane = tid & 63;

    {   // stage x rows (coalesced read, padded transpose write)
        const int lq = tid >> 6, m = tid & 63;
        xT[m][lq]     = x[((size_t)b * LL + l0 + lq) * FF + m];
        xT[m][lq + 4] = x[((size_t)b * LL + l0 + lq + 4) * FF + m];
    }
    __syncthreads();

    float racc[8];
    #pragma unroll
    for (int q = 0; q < 8; ++q) racc[q] = 0.f;
    float mn = INFINITY;

    const int jbase = wave * 16;
    const float4* spb = (const float4*)(slabJ + ((size_t)jbase * FF + lane) * FF);
    // double-buffered slab slice in registers; j-loop unrolled by 2
    float4 srA[16], srB[16];
    #pragma unroll
    for (int q = 0; q < 16; ++q) srA[q] = spb[q];
    #pragma unroll 1
    for (int jj = 0; jj < 16; jj += 2) {
        {   // prefetch j+1
            const float4* spn = (const float4*)(slabJ + ((size_t)(jbase + jj + 1) * FF + lane) * FF);
            #pragma unroll
            for (int q = 0; q < 16; ++q) srB[q] = spn[q];
        }
        COMPUTE_J(srA, jbase + jj);
        if (jj + 2 < 16) {   // prefetch j+2
            const float4* spn = (const float4*)(slabJ + ((size_t)(jbase + jj + 2) * FF + lane) * FF);
            #pragma unroll
            for (int q = 0; q < 16; ++q) srA[q] = spn[q];
        }
        COMPUTE_J(srB, jbase + jj + 1);
    }

    // deterministic cross-wave j-reduction
    #pragma unroll
    for (int lq = 0; lq < 8; ++lq) part[wave][lq][lane] = racc[lq];
    #pragma unroll
    for (int o = 32; o; o >>= 1) mn = fminf(mn, __shfl_xor(mn, o));
    if (lane == 0) mnred[wave] = mn;
    __syncthreads();
    {
        const int lq = tid >> 6, i = tid & 63;
        float a0 = (part[0][lq][i] + part[1][lq][i]) + (part[2][lq][i] + part[3][lq][i]);
        out[((size_t)b * LL + l0 + lq) * FF + i] = a0;
        float a1 = (part[0][lq + 4][i] + part[1][lq + 4][i]) + (part[2][lq + 4][i] + part[3][lq + 4][i]);
        out[((size_t)b * LL + l0 + lq + 4) * FF + i] = a1;
        if (tid == 0) {
            float m2 = fminf(fminf(mnred[0], mnred[1]), fminf(mnred[2], mnred[3]));
            if (!(m2 >= 10.5f)) atomicOr(flag, 1);   // also catches NaN
        }
    }
}

// ==================== exact sequential fallback / repair (verified round-1) ====================
__launch_bounds__(1024, 1)
__global__ void coil_main(const float* __restrict__ x,
                          const float* __restrict__ inter,
                          const float* __restrict__ slab0T,
                          float* __restrict__ out,
                          int useSlab,
                          const int* __restrict__ flag) {
    if (flag && *flag == 0) return;   // certificate held: parallel path already correct

    __shared__ float Tlds[FF][FP1];
    __shared__ float selr[FF][FP1];
    __shared__ float s_l[FF], hiW[FF], loW[FF];
    __shared__ float zsc[FP1], swW[FP1], scoresAcc[FP1];
    __shared__ float chunkA[8][FP1 + 3];
    __shared__ int IL[FF], JL[FF];
    __shared__ int nIJ[2];
    __shared__ int Klist[FP1];
    __shared__ float Kw[FP1];
    __shared__ int nK;
    __shared__ float redmx;

    const int b = blockIdx.x;
    const int tid = threadIdx.x;
    const int wave = tid >> 6;
    const int lane = tid & 63;

    for (int idx = tid; idx < FF * FP1; idx += 1024)
        ((float*)Tlds)[idx] = 1.0f / FF;

    const float* xb = x + (size_t)b * LL * FF;
    float* out0 = out + (size_t)b * LL * FF;
    float* out1 = out + (size_t)BB * LL * FF + (size_t)b * FF * FF;

    for (int l = 0; l < LL; ++l) {
        __syncthreads();
        if (tid < FF) s_l[tid] = xb[l * FF + tid];
        __syncthreads();
        if (wave == 0) {
            float z = s_l[lane] / 0.001f;
            float mx = z;
            for (int o = 32; o > 0; o >>= 1) mx = fmaxf(mx, __shfl_xor(mx, o));
            float e = expf(z - mx);
            float sm = e;
            for (int o = 32; o > 0; o >>= 1) sm += __shfl_xor(sm, o);
            float w = e / sm;
            hiW[lane] = w;
            unsigned long long msk = __ballot(w > 1e-16f);
            int pos = (int)__popcll(msk & ((1ull << lane) - 1ull));
            if (w > 1e-16f) JL[pos] = lane;
            if (lane == 0) nIJ[1] = (int)__popcll(msk);
        } else if (wave == 1) {
            float z = 1.0f - s_l[lane] / 0.001f;
            float mx = z;
            for (int o = 32; o > 0; o >>= 1) mx = fmaxf(mx, __shfl_xor(mx, o));
            float e = expf(z - mx);
            float sm = e;
            for (int o = 32; o > 0; o >>= 1) sm += __shfl_xor(sm, o);
            float w = e / sm;
            loW[lane] = w;
            unsigned long long msk = __ballot(w > 1e-16f);
            int pos = (int)__popcll(msk & ((1ull << lane) - 1ull));
            if (w > 1e-16f) IL[pos] = lane;
            if (lane == 0) nIJ[0] = (int)__popcll(msk);
        }
        if (tid < FP1) scoresAcc[tid] = 0.0f;
        __syncthreads();

        const int nI = nIJ[0], nJ = nIJ[1];
        const int npairs = nI * nJ;
        for (int pbase = 0; pbase < npairs; pbase += 8) {
            int prem = npairs - pbase; if (prem > 8) prem = 8;
            int p_local = wave >> 1, half = wave & 1;
            if (p_local < prem) {
                int p = pbase + p_local;
                int i = IL[p / nJ];
                int jx = JL[p % nJ];
                float vv = loW[i] * hiW[jx];
                int k = half * 32 + lane;
                bool act = half ? (lane < 33) : (lane < 32);
                if (act) {
                    const float* base = inter + (size_t)(i * FF + jx) * (FF * FP1) + k;
                    const float* nsv = (k == 0) ? s_l : &Tlds[k - 1][0];
                    float acc = 0.0f;
                    #pragma unroll 16
                    for (int m = 0; m < FF; ++m) acc += base[m * FP1] * nsv[m];
                    chunkA[p_local][k] = vv * acc;
                }
            }
            __syncthreads();
            if (tid < FP1) {
                float a = scoresAcc[tid];
                for (int pl = 0; pl < prem; ++pl) a += chunkA[pl][tid];
                scoresAcc[tid] = a;
            }
            __syncthreads();
        }
        if (tid < FP1) zsc[tid] = scoresAcc[tid] / 0.001f;
        __syncthreads();
        if (tid == 0) {
            float mx = zsc[0];
            for (int k = 1; k < FP1; ++k) mx = fmaxf(mx, zsc[k]);
            redmx = mx;
        }
        __syncthreads();
        if (tid < FP1) zsc[tid] = expf(zsc[tid] - redmx);
        __syncthreads();
        if (tid == 0) {
            float sm = 0.0f;
            for (int k = 0; k < FP1; ++k) sm += zsc[k];
            int cnt = 0;
            for (int k = 0; k < FP1; ++k) {
                float w = zsc[k] / sm;
                swW[k] = w;
                if (w > 1e-14f) { Klist[cnt] = k; Kw[cnt] = w; ++cnt; }
            }
            nK = cnt;
        }
        __syncthreads();

        float ax = 0.f, ay = 0.f, az = 0.f, aw = 0.f;
        const int ij0 = tid * 4;
        for (int kk = 0; kk < nK; ++kk) {
            int k = Klist[kk];
            float wk = Kw[kk];
            float dx = 0.f, dy = 0.f, dz = 0.f, dw = 0.f;
            if (k == 0 && useSlab) {
                const float4* sp = (const float4*)slab0T;
                #pragma unroll 8
                for (int m = 0; m < FF; ++m) {
                    float4 f = sp[m * (FF * FF / 4) + tid];
                    float ns = s_l[m];
                    dx += f.x * ns; dy += f.y * ns; dz += f.z * ns; dw += f.w * ns;
                }
            } else {
                const float* nsv = (k == 0) ? s_l : &Tlds[k - 1][0];
                const float* bp = inter + (size_t)ij0 * (FF * FP1) + k;
                #pragma unroll 8
                for (int m = 0; m < FF; ++m) {
                    float ns = nsv[m];
                    dx += bp[m * FP1] * ns;
                    dy += bp[m * FP1 + FF * FP1] * ns;
                    dz += bp[m * FP1 + 2 * FF * FP1] * ns;
                    dw += bp[m * FP1 + 3 * FF * FP1] * ns;
                }
            }
            ax += wk * dx; ay += wk * dy; az += wk * dz; aw += wk * dw;
        }
        {
            int ii = tid >> 4;
            int jj = (tid & 15) * 4;
            selr[jj + 0][ii] = ax; selr[jj + 1][ii] = ay;
            selr[jj + 2][ii] = az; selr[jj + 3][ii] = aw;
        }
        __syncthreads();
        if (tid < FF) {
            int jcol = tid;
            float mx = -INFINITY;
            for (int i2 = 0; i2 < FF; ++i2) mx = fmaxf(mx, selr[jcol][i2] * 7.0f);
            float sm = 0.0f;
            for (int i2 = 0; i2 < FF; ++i2) {
                float e = expf(selr[jcol][i2] * 7.0f - mx);
                selr[jcol][i2] = e; sm += e;
            }
            for (int i2 = 0; i2 < FF; ++i2) Tlds[jcol][i2] = selr[jcol][i2] / sm;
        }
        __syncthreads();
        if (tid < FF) {
            float acc2 = 0.0f;
            for (int j2 = 0; j2 < FF; ++j2) acc2 += Tlds[j2][tid] * s_l[j2];
            out0[l * FF + tid] = acc2;
        }
    }
    __syncthreads();
    for (int idx = tid; idx < FF * FF; idx += 1024) {
        int i2 = idx >> 6, j2 = idx & 63;
        out1[idx] = Tlds[j2][i2];
    }
}

extern "C" void kernel_launch(void* const* d_in, const int* in_sizes, int n_in,
                              void* d_out, int out_size, void* d_ws, size_t ws_size,
                              hipStream_t stream) {
    const float* x = (const float*)d_in[0];
    const float* inter = (const float*)d_in[1];
    float* outp = (float*)d_out;
    char* ws = (char*)d_ws;

    if (ws_size >= WS_NEED) {
        float* slabJ = (float*)(ws + OFF_SLABJ);
        int* flag = (int*)(ws + OFF_FLAG);

        build_slabJ<<<dim3((FF * FF * FF + 255) / 256), dim3(256), 0, stream>>>(inter, slabJ, flag);
        fused_scan<<<dim3(BB, 16), dim3(256), 0, stream>>>(x, slabJ, outp, flag);
        // repair: no-op when certificate holds; exact recompute otherwise
        coil_main<<<dim3(BB), dim3(1024), 0, stream>>>(x, inter, (const float*)0, outp, 0, flag);
    } else {
        float* slab0T = (float*)ws;
        int useSlab = (ws_size >= (size_t)FF * FF * FF * sizeof(float)) ? 1 : 0;
        if (useSlab)
            build_slab0<<<dim3((FF * FF * FF + 255) / 256), dim3(256), 0, stream>>>(inter, slab0T);
        coil_main<<<dim3(BB), dim3(1024), 0, stream>>>(x, inter, slab0T, outp, useSlab, (const int*)0);
    }
}

// Round 5
// 68.912 us; speedup vs baseline: 5.8716x; 5.8716x over previous
//
#include <hip/hip_runtime.h>
#include <math.h>

#define FF 64
#define FP1 65
#define BB 32
#define LL 128
#define NBL 4096        // BB*LL
#define NIJ 4096        // FF*FF

// ---- ws layout (bytes) ----
#define OFF_SLAB0 0ull                  // slab0T[m][ij]: 64*4096*4 = 1,048,576
#define OFF_D0    1048576ull            // 4096*4096*4 = 67,108,864
#define OFF_FLAG  68157440ull           // 4 B
#define WS_NEED   68157504ull

// ============ stage 1: slab0T[m][ij] = inter[i][j][m][0]; zero flag ============
__global__ void build_slab0(const float* __restrict__ inter, float* __restrict__ slab0T,
                            int* __restrict__ flag) {
    int t = blockIdx.x * blockDim.x + threadIdx.x;
    if (t == 0 && flag) *flag = 0;
    if (t < FF * FF * FF) {
        int m = t >> 12;
        int ij = t & 4095;
        slab0T[t] = inter[((size_t)ij * FF + m) * FP1];
    }
}

// ============ stage 2: D0[bl][ij] = sum_m slab0T[m][ij] * x[bl][m]  (f32) ============
// grid (32 b, 16 sl), block 1024 = 16 waves; wave owns 8 l-rows; lane owns 4 ij.
// x read via wave-uniform scalar loads (no LDS x-tile) -> LDS = 64 KB -> 2 blocks/CU.
__launch_bounds__(1024)
__global__ void d0_pass(const float* __restrict__ x,
                        const float* __restrict__ slab0T,
                        float* __restrict__ D0) {
    __shared__ __align__(16) float slds[FF][256];   // 64 KB
    const int tid = threadIdx.x;
    const int b = blockIdx.x, sl = blockIdx.y;
    const int ij0g = sl * 256;
    {   // stage 64x256 slab slice: 4096 float4 by 1024 threads, coalesced
        const float4* src = (const float4*)(slab0T + ij0g);  // row stride = 1024 float4
        float4* dst = (float4*)slds;
        #pragma unroll
        for (int q = 0; q < 4; ++q) {
            const int idx = tid + q * 1024;          // 0..4095
            const int m = idx >> 6, c = idx & 63;
            dst[idx] = src[(size_t)m * 1024 + c];
        }
    }
    __syncthreads();
    const int wv = tid >> 6, lane = tid & 63;
    const float* xr = x + ((size_t)b * LL + wv * 8) * FF;   // wave-uniform base
    float4 acc[8];
    #pragma unroll
    for (int e = 0; e < 8; ++e) acc[e] = make_float4(0.f, 0.f, 0.f, 0.f);
    #pragma unroll 4
    for (int m = 0; m < FF; ++m) {
        const float4 sv = *(const float4*)&slds[m][lane * 4];
        #pragma unroll
        for (int e = 0; e < 8; ++e) {
            const float xv = xr[e * FF + m];        // uniform -> s_load + v_fmac(v,s,v)
            acc[e].x += xv * sv.x; acc[e].y += xv * sv.y;
            acc[e].z += xv * sv.z; acc[e].w += xv * sv.w;
        }
    }
    #pragma unroll
    for (int e = 0; e < 8; ++e)
        *(float4*)(D0 + ((size_t)b * LL + wv * 8 + e) * NIJ + ij0g + lane * 4) = acc[e];
}

// ============ stage 3: per-(b,l) col-softmax(7*D0) -> out row; certificate min ============
__launch_bounds__(256)
__global__ void tsm_out(const float* __restrict__ x,
                        const float* __restrict__ D0,
                        float* __restrict__ out,
                        int* __restrict__ flag) {
    __shared__ __align__(16) float D0l[NIJ];        // 16 KB
    __shared__ float Tl[FF][FP1];                   // 16.6 KB
    __shared__ float xl[FF];
    __shared__ float wmn[4];
    const int bl = blockIdx.x;
    const int b = bl >> 7, l = bl & 127;
    const int t = threadIdx.x;

    {
        const float4* dr = (const float4*)(D0 + (size_t)bl * NIJ);
        float4* dl = (float4*)D0l;
        #pragma unroll
        for (int q = 0; q < 4; ++q) dl[t + 256 * q] = dr[t + 256 * q];
        if (t < 16) ((float4*)xl)[t] = ((const float4*)(x + (size_t)bl * FF))[t];
    }
    __syncthreads();

    // softmax over i (rows) per column j of sel[i][j] = D0l[i*64+j]*7
    const int j = t >> 2, iq = t & 3;     // 4 threads per column, 16 i each
    float v[16];
    float mx = -INFINITY, mn = INFINITY;
    #pragma unroll
    for (int r = 0; r < 16; ++r) {
        float q = D0l[(iq * 16 + r) * 64 + j] * 7.0f;
        v[r] = q;
        mx = fmaxf(mx, q);
        mn = fminf(mn, q);
    }
    mx = fmaxf(mx, __shfl_xor(mx, 1));
    mx = fmaxf(mx, __shfl_xor(mx, 2));
    float sm = 0.f;
    #pragma unroll
    for (int r = 0; r < 16; ++r) {
        float e = expf(v[r] - mx);
        v[r] = e; sm += e;
    }
    sm += __shfl_xor(sm, 1);
    sm += __shfl_xor(sm, 2);
    const float inv = 1.0f / sm;
    #pragma unroll
    for (int r = 0; r < 16; ++r)
        Tl[iq * 16 + r][j] = v[r] * inv;

    // certificate: min over ij of 7*D0 must be >= 10.5 (i.e. min D0 >= 1.5)
    #pragma unroll
    for (int o = 32; o; o >>= 1) mn = fminf(mn, __shfl_xor(mn, o));
    if ((t & 63) == 0) wmn[t >> 6] = mn;
    __syncthreads();
    if (t == 0) {
        float m2 = fminf(fminf(wmn[0], wmn[1]), fminf(wmn[2], wmn[3]));
        if (!(m2 >= 10.5f)) atomicOr(flag, 1);   // also catches NaN
    }

    // out0[bl][i] = sum_j Tl[i][j] * xl[j]
    const int i = t >> 2, jq = t & 3;
    float acc = 0.f;
    #pragma unroll
    for (int r = 0; r < 16; ++r) {
        const int jj = jq * 16 + r;
        acc += Tl[i][jj] * xl[jj];
    }
    acc += __shfl_xor(acc, 1);
    acc += __shfl_xor(acc, 2);
    if (jq == 0) out[(size_t)bl * FF + i] = acc;

    if (l == LL - 1) {
        #pragma unroll
        for (int q = 0; q < 16; ++q) {
            const int idx = t + 256 * q;
            out[(size_t)BB * LL * FF + (size_t)b * NIJ + idx] = Tl[idx >> 6][idx & 63];
        }
    }
}

// ==================== exact sequential fallback / repair (verified round-1) ====================
__launch_bounds__(1024, 1)
__global__ void coil_main(const float* __restrict__ x,
                          const float* __restrict__ inter,
                          const float* __restrict__ slab0T,
                          float* __restrict__ out,
                          int useSlab,
                          const int* __restrict__ flag) {
    if (flag && *flag == 0) return;   // certificate held: parallel path already correct

    __shared__ float Tlds[FF][FP1];
    __shared__ float selr[FF][FP1];
    __shared__ float s_l[FF], hiW[FF], loW[FF];
    __shared__ float zsc[FP1], swW[FP1], scoresAcc[FP1];
    __shared__ float chunkA[8][FP1 + 3];
    __shared__ int IL[FF], JL[FF];
    __shared__ int nIJ[2];
    __shared__ int Klist[FP1];
    __shared__ float Kw[FP1];
    __shared__ int nK;
    __shared__ float redmx;

    const int b = blockIdx.x;
    const int tid = threadIdx.x;
    const int wave = tid >> 6;
    const int lane = tid & 63;

    for (int idx = tid; idx < FF * FP1; idx += 1024)
        ((float*)Tlds)[idx] = 1.0f / FF;

    const float* xb = x + (size_t)b * LL * FF;
    float* out0 = out + (size_t)b * LL * FF;
    float* out1 = out + (size_t)BB * LL * FF + (size_t)b * FF * FF;

    for (int l = 0; l < LL; ++l) {
        __syncthreads();
        if (tid < FF) s_l[tid] = xb[l * FF + tid];
        __syncthreads();
        if (wave == 0) {
            float z = s_l[lane] / 0.001f;
            float mx = z;
            for (int o = 32; o > 0; o >>= 1) mx = fmaxf(mx, __shfl_xor(mx, o));
            float e = expf(z - mx);
            float sm = e;
            for (int o = 32; o > 0; o >>= 1) sm += __shfl_xor(sm, o);
            float w = e / sm;
            hiW[lane] = w;
            unsigned long long msk = __ballot(w > 1e-16f);
            int pos = (int)__popcll(msk & ((1ull << lane) - 1ull));
            if (w > 1e-16f) JL[pos] = lane;
            if (lane == 0) nIJ[1] = (int)__popcll(msk);
        } else if (wave == 1) {
            float z = 1.0f - s_l[lane] / 0.001f;
            float mx = z;
            for (int o = 32; o > 0; o >>= 1) mx = fmaxf(mx, __shfl_xor(mx, o));
            float e = expf(z - mx);
            float sm = e;
            for (int o = 32; o > 0; o >>= 1) sm += __shfl_xor(sm, o);
            float w = e / sm;
            loW[lane] = w;
            unsigned long long msk = __ballot(w > 1e-16f);
            int pos = (int)__popcll(msk & ((1ull << lane) - 1ull));
            if (w > 1e-16f) IL[pos] = lane;
            if (lane == 0) nIJ[0] = (int)__popcll(msk);
        }
        if (tid < FP1) scoresAcc[tid] = 0.0f;
        __syncthreads();

        const int nI = nIJ[0], nJ = nIJ[1];
        const int npairs = nI * nJ;
        for (int pbase = 0; pbase < npairs; pbase += 8) {
            int prem = npairs - pbase; if (prem > 8) prem = 8;
            int p_local = wave >> 1, half = wave & 1;
            if (p_local < prem) {
                int p = pbase + p_local;
                int i = IL[p / nJ];
                int jx = JL[p % nJ];
                float vv = loW[i] * hiW[jx];
                int k = half * 32 + lane;
                bool act = half ? (lane < 33) : (lane < 32);
                if (act) {
                    const float* base = inter + (size_t)(i * FF + jx) * (FF * FP1) + k;
                    const float* nsv = (k == 0) ? s_l : &Tlds[k - 1][0];
                    float acc = 0.0f;
                    #pragma unroll 16
                    for (int m = 0; m < FF; ++m) acc += base[m * FP1] * nsv[m];
                    chunkA[p_local][k] = vv * acc;
                }
            }
            __syncthreads();
            if (tid < FP1) {
                float a = scoresAcc[tid];
                for (int pl = 0; pl < prem; ++pl) a += chunkA[pl][tid];
                scoresAcc[tid] = a;
            }
            __syncthreads();
        }
        if (tid < FP1) zsc[tid] = scoresAcc[tid] / 0.001f;
        __syncthreads();
        if (tid == 0) {
            float mx = zsc[0];
            for (int k = 1; k < FP1; ++k) mx = fmaxf(mx, zsc[k]);
            redmx = mx;
        }
        __syncthreads();
        if (tid < FP1) zsc[tid] = expf(zsc[tid] - redmx);
        __syncthreads();
        if (tid == 0) {
            float sm = 0.0f;
            for (int k = 0; k < FP1; ++k) sm += zsc[k];
            int cnt = 0;
            for (int k = 0; k < FP1; ++k) {
                float w = zsc[k] / sm;
                swW[k] = w;
                if (w > 1e-14f) { Klist[cnt] = k; Kw[cnt] = w; ++cnt; }
            }
            nK = cnt;
        }
        __syncthreads();

        float ax = 0.f, ay = 0.f, az = 0.f, aw = 0.f;
        const int ij0 = tid * 4;
        for (int kk = 0; kk < nK; ++kk) {
            int k = Klist[kk];
            float wk = Kw[kk];
            float dx = 0.f, dy = 0.f, dz = 0.f, dw = 0.f;
            if (k == 0 && useSlab) {
                const float4* sp = (const float4*)slab0T;
                #pragma unroll 8
                for (int m = 0; m < FF; ++m) {
                    float4 f = sp[m * (FF * FF / 4) + tid];
                    float ns = s_l[m];
                    dx += f.x * ns; dy += f.y * ns; dz += f.z * ns; dw += f.w * ns;
                }
            } else {
                const float* nsv = (k == 0) ? s_l : &Tlds[k - 1][0];
                const float* bp = inter + (size_t)ij0 * (FF * FP1) + k;
                #pragma unroll 8
                for (int m = 0; m < FF; ++m) {
                    float ns = nsv[m];
                    dx += bp[m * FP1] * ns;
                    dy += bp[m * FP1 + FF * FP1] * ns;
                    dz += bp[m * FP1 + 2 * FF * FP1] * ns;
                    dw += bp[m * FP1 + 3 * FF * FP1] * ns;
                }
            }
            ax += wk * dx; ay += wk * dy; az += wk * dz; aw += wk * dw;
        }
        {
            int ii = tid >> 4;
            int jj = (tid & 15) * 4;
            selr[jj + 0][ii] = ax; selr[jj + 1][ii] = ay;
            selr[jj + 2][ii] = az; selr[jj + 3][ii] = aw;
        }
        __syncthreads();
        if (tid < FF) {
            int jcol = tid;
            float mx = -INFINITY;
            for (int i2 = 0; i2 < FF; ++i2) mx = fmaxf(mx, selr[jcol][i2] * 7.0f);
            float sm = 0.0f;
            for (int i2 = 0; i2 < FF; ++i2) {
                float e = expf(selr[jcol][i2] * 7.0f - mx);
                selr[jcol][i2] = e; sm += e;
            }
            for (int i2 = 0; i2 < FF; ++i2) Tlds[jcol][i2] = selr[jcol][i2] / sm;
        }
        __syncthreads();
        if (tid < FF) {
            float acc2 = 0.0f;
            for (int j2 = 0; j2 < FF; ++j2) acc2 += Tlds[j2][tid] * s_l[j2];
            out0[l * FF + tid] = acc2;
        }
    }
    __syncthreads();
    for (int idx = tid; idx < FF * FF; idx += 1024) {
        int i2 = idx >> 6, j2 = idx & 63;
        out1[idx] = Tlds[j2][i2];
    }
}

extern "C" void kernel_launch(void* const* d_in, const int* in_sizes, int n_in,
                              void* d_out, int out_size, void* d_ws, size_t ws_size,
                              hipStream_t stream) {
    const float* x = (const float*)d_in[0];
    const float* inter = (const float*)d_in[1];
    float* outp = (float*)d_out;
    char* ws = (char*)d_ws;

    if (ws_size >= WS_NEED) {
        float* slab0T = (float*)(ws + OFF_SLAB0);
        float* D0 = (float*)(ws + OFF_D0);
        int* flag = (int*)(ws + OFF_FLAG);

        build_slab0<<<dim3(1024), dim3(256), 0, stream>>>(inter, slab0T, flag);
        d0_pass<<<dim3(32, 16), dim3(1024), 0, stream>>>(x, slab0T, D0);
        tsm_out<<<dim3(NBL), dim3(256), 0, stream>>>(x, D0, outp, flag);
        // repair: no-op when certificate holds; exact recompute otherwise
        coil_main<<<dim3(BB), dim3(1024), 0, stream>>>(x, inter, slab0T, outp, 1, flag);
    } else {
        float* slab0T = (float*)ws;
        int useSlab = (ws_size >= (size_t)FF * FF * FF * sizeof(float)) ? 1 : 0;
        if (useSlab)
            build_slab0<<<dim3(1024), dim3(256), 0, stream>>>(inter, slab0T, (int*)0);
        coil_main<<<dim3(BB), dim3(1024), 0, stream>>>(x, inter, slab0T, outp, useSlab, (const int*)0);
    }
}

// Round 6
// 44.868 us; speedup vs baseline: 9.0181x; 1.5359x over previous
//
#include <hip/hip_runtime.h>
#include <math.h>

#define FF 64
#define FP1 65
#define BB 32
#define LL 128
#define NBL 4096        // BB*LL
#define NIJ 4096        // FF*FF

typedef __attribute__((ext_vector_type(8))) short short8;
typedef __attribute__((ext_vector_type(4))) float f32x4;

__device__ __forceinline__ unsigned short f2b(float f) {   // f32 -> bf16 RNE
    union { float f; unsigned u; } v; v.f = f;
    unsigned r = v.u + 0x7fffu + ((v.u >> 16) & 1u);
    return (unsigned short)(r >> 16);
}
__device__ __forceinline__ float b2f(unsigned short h) {
    union { unsigned u; float f; } v; v.u = ((unsigned)h) << 16; return v.f;
}

// ---- ws layout (bytes) ----
#define OFF_XH   0ull            // xA hi  [2][256][64][8] ushort = 512 KB
#define OFF_XL   524288ull       // xA lo  512 KB
#define OFF_BH   1048576ull      // slabB hi [2][256][64][8] ushort = 512 KB
#define OFF_BL   1572864ull      // slabB lo 512 KB
#define OFF_D0   2097152ull      // D0 f32 [4096][4096] = 67,108,864
#define OFF_FLAG 69206016ull     // 4 B
#define WS_NEED  69206080ull

// ============ stage 1a: slab -> bf16 hi/lo in MFMA-B-fragment order ============
// idx t = ((ks*256+fn)*64+lane)*8+e ; value = inter[ij][m][k=0],
// ij = fn*16+(lane&15), m = ks*32+((lane>>4)&3)*8+e
__global__ void build_slabB(const float* __restrict__ inter,
                            unsigned short* __restrict__ bH,
                            unsigned short* __restrict__ bL) {
    const size_t t = (size_t)blockIdx.x * 256 + threadIdx.x;   // 262144 total
    const int e = (int)(t & 7);
    const int lane = (int)((t >> 3) & 63);
    const int fn = (int)((t >> 9) & 255);
    const int ks = (int)(t >> 17);
    const int m = ks * 32 + ((lane >> 4) & 3) * 8 + e;
    const int ij = fn * 16 + (lane & 15);
    const float v = inter[((size_t)ij * FF + m) * FP1];
    const unsigned short h = f2b(v);
    bH[t] = h;
    bL[t] = f2b(v - b2f(h));
}

// ============ stage 1b: x -> bf16 hi/lo in MFMA-A-fragment order; zero flag ============
// t = (ks*256+fm)*64+lane ; bl = fm*16+(lane&15), feat = ks*32+((lane>>4)&3)*8 + e
__global__ void build_xA(const float* __restrict__ x,
                         unsigned short* __restrict__ xH,
                         unsigned short* __restrict__ xL,
                         int* __restrict__ flag) {
    const int t = blockIdx.x * 256 + threadIdx.x;   // 32768 total
    if (t == 0) *flag = 0;
    const int lane = t & 63;
    const int fm = (t >> 6) & 255;
    const int ks = t >> 14;
    const int bl = fm * 16 + (lane & 15);
    const int fb = ks * 32 + ((lane >> 4) & 3) * 8;
    const float4 v0 = *(const float4*)(x + (size_t)bl * FF + fb);
    const float4 v1 = *(const float4*)(x + (size_t)bl * FF + fb + 4);
    float vv[8] = {v0.x, v0.y, v0.z, v0.w, v1.x, v1.y, v1.z, v1.w};
    unsigned short hh[8], ll[8];
    #pragma unroll
    for (int e = 0; e < 8; ++e) {
        hh[e] = f2b(vv[e]);
        ll[e] = f2b(vv[e] - b2f(hh[e]));
    }
    *(short8*)(xH + (size_t)t * 8) = *(const short8*)hh;
    *(short8*)(xL + (size_t)t * 8) = *(const short8*)ll;
}

// ============ stage 2: D0 = x . slab via split-bf16 MFMA (no LDS, no barriers) ============
// grid (32,32), block 256 = 4 waves (2x2). Wave tile 64x64; 16 16x16 frags; K=64.
__launch_bounds__(256)
__global__ void d0_mfma(const unsigned short* __restrict__ xH,
                        const unsigned short* __restrict__ xL,
                        const unsigned short* __restrict__ bH,
                        const unsigned short* __restrict__ bL,
                        float* __restrict__ D0) {
    const int tid = threadIdx.x;
    const int w = tid >> 6, lane = tid & 63;
    const int fm0 = blockIdx.x * 8 + (w >> 1) * 4;   // A-frag base (16 bl per frag)
    const int fn0 = blockIdx.y * 8 + (w & 1) * 4;    // B-frag base (16 ij per frag)

    f32x4 acc[4][4];
    #pragma unroll
    for (int i = 0; i < 4; ++i)
        #pragma unroll
        for (int j = 0; j < 4; ++j) acc[i][j] = (f32x4){0.f, 0.f, 0.f, 0.f};

    #pragma unroll
    for (int ks = 0; ks < 2; ++ks) {
        short8 aH[4], aL[4], bHf[4], bLf[4];
        #pragma unroll
        for (int q = 0; q < 4; ++q) {
            const size_t ab = (((size_t)ks * 256 + fm0 + q) * 64 + lane) * 8;
            aH[q] = *(const short8*)(xH + ab);
            aL[q] = *(const short8*)(xL + ab);
            const size_t bb = (((size_t)ks * 256 + fn0 + q) * 64 + lane) * 8;
            bHf[q] = *(const short8*)(bH + bb);
            bLf[q] = *(const short8*)(bL + bb);
        }
        #pragma unroll
        for (int i = 0; i < 4; ++i)
            #pragma unroll
            for (int j = 0; j < 4; ++j) {
                acc[i][j] = __builtin_amdgcn_mfma_f32_16x16x32_bf16(aH[i], bHf[j], acc[i][j], 0, 0, 0);
                acc[i][j] = __builtin_amdgcn_mfma_f32_16x16x32_bf16(aH[i], bLf[j], acc[i][j], 0, 0, 0);
                acc[i][j] = __builtin_amdgcn_mfma_f32_16x16x32_bf16(aL[i], bHf[j], acc[i][j], 0, 0, 0);
            }
    }

    // epilogue: C[row=bl][col=ij]; col=lane&15, row=(lane>>4)*4+reg
    const int rbase = (fm0) * 16 + (lane >> 4) * 4;
    const int cbase = (fn0) * 16 + (lane & 15);
    #pragma unroll
    for (int i = 0; i < 4; ++i)
        #pragma unroll
        for (int j = 0; j < 4; ++j)
            #pragma unroll
            for (int r = 0; r < 4; ++r)
                D0[(size_t)(rbase + i * 16 + r) * NIJ + cbase + j * 16] = acc[i][j][r];
}

// ============ stage 3: per-(b,l) col-softmax(7*D0) -> out row; certificate min ============
__launch_bounds__(256)
__global__ void tsm_out(const float* __restrict__ x,
                        const float* __restrict__ D0,
                        float* __restrict__ out,
                        int* __restrict__ flag) {
    __shared__ __align__(16) float D0l[NIJ];        // 16 KB
    __shared__ float Tl[FF][FP1];                   // 16.6 KB
    __shared__ float xl[FF];
    __shared__ float wmn[4];
    const int bl = blockIdx.x;
    const int b = bl >> 7, l = bl & 127;
    const int t = threadIdx.x;

    {
        const float4* dr = (const float4*)(D0 + (size_t)bl * NIJ);
        float4* dl = (float4*)D0l;
        #pragma unroll
        for (int q = 0; q < 4; ++q) dl[t + 256 * q] = dr[t + 256 * q];
        if (t < 16) ((float4*)xl)[t] = ((const float4*)(x + (size_t)bl * FF))[t];
    }
    __syncthreads();

    // softmax over i (rows) per column j of sel[i][j] = D0l[i*64+j]*7
    const int j = t >> 2, iq = t & 3;     // 4 threads per column, 16 i each
    float v[16];
    float mx = -INFINITY, mn = INFINITY;
    #pragma unroll
    for (int r = 0; r < 16; ++r) {
        float q = D0l[(iq * 16 + r) * 64 + j] * 7.0f;
        v[r] = q;
        mx = fmaxf(mx, q);
        mn = fminf(mn, q);
    }
    mx = fmaxf(mx, __shfl_xor(mx, 1));
    mx = fmaxf(mx, __shfl_xor(mx, 2));
    float sm = 0.f;
    #pragma unroll
    for (int r = 0; r < 16; ++r) {
        float e = expf(v[r] - mx);
        v[r] = e; sm += e;
    }
    sm += __shfl_xor(sm, 1);
    sm += __shfl_xor(sm, 2);
    const float inv = 1.0f / sm;
    #pragma unroll
    for (int r = 0; r < 16; ++r)
        Tl[iq * 16 + r][j] = v[r] * inv;

    // certificate: min over ij of 7*D0 must be >= 10.5 (i.e. min D0 >= 1.5)
    #pragma unroll
    for (int o = 32; o; o >>= 1) mn = fminf(mn, __shfl_xor(mn, o));
    if ((t & 63) == 0) wmn[t >> 6] = mn;
    __syncthreads();
    if (t == 0) {
        float m2 = fminf(fminf(wmn[0], wmn[1]), fminf(wmn[2], wmn[3]));
        if (!(m2 >= 10.5f)) atomicOr(flag, 1);   // also catches NaN
    }

    // out0[bl][i] = sum_j Tl[i][j] * xl[j]
    const int i = t >> 2, jq = t & 3;
    float acc = 0.f;
    #pragma unroll
    for (int r = 0; r < 16; ++r) {
        const int jj = jq * 16 + r;
        acc += Tl[i][jj] * xl[jj];
    }
    acc += __shfl_xor(acc, 1);
    acc += __shfl_xor(acc, 2);
    if (jq == 0) out[(size_t)bl * FF + i] = acc;

    if (l == LL - 1) {
        #pragma unroll
        for (int q = 0; q < 16; ++q) {
            const int idx = t + 256 * q;
            out[(size_t)BB * LL * FF + (size_t)b * NIJ + idx] = Tl[idx >> 6][idx & 63];
        }
    }
}

// ============ fallback slab build (small-ws path only) ============
__global__ void build_slab0(const float* __restrict__ inter, float* __restrict__ slab0T) {
    int t = blockIdx.x * blockDim.x + threadIdx.x;
    if (t < FF * FF * FF) {
        int m = t >> 12;
        int ij = t & 4095;
        slab0T[t] = inter[((size_t)ij * FF + m) * FP1];
    }
}

// ==================== exact sequential fallback / repair (verified round-1) ====================
__launch_bounds__(1024, 1)
__global__ void coil_main(const float* __restrict__ x,
                          const float* __restrict__ inter,
                          const float* __restrict__ slab0T,
                          float* __restrict__ out,
                          int useSlab,
                          const int* __restrict__ flag) {
    if (flag && *flag == 0) return;   // certificate held: parallel path already correct

    __shared__ float Tlds[FF][FP1];
    __shared__ float selr[FF][FP1];
    __shared__ float s_l[FF], hiW[FF], loW[FF];
    __shared__ float zsc[FP1], swW[FP1], scoresAcc[FP1];
    __shared__ float chunkA[8][FP1 + 3];
    __shared__ int IL[FF], JL[FF];
    __shared__ int nIJ[2];
    __shared__ int Klist[FP1];
    __shared__ float Kw[FP1];
    __shared__ int nK;
    __shared__ float redmx;

    const int b = blockIdx.x;
    const int tid = threadIdx.x;
    const int wave = tid >> 6;
    const int lane = tid & 63;

    for (int idx = tid; idx < FF * FP1; idx += 1024)
        ((float*)Tlds)[idx] = 1.0f / FF;

    const float* xb = x + (size_t)b * LL * FF;
    float* out0 = out + (size_t)b * LL * FF;
    float* out1 = out + (size_t)BB * LL * FF + (size_t)b * FF * FF;

    for (int l = 0; l < LL; ++l) {
        __syncthreads();
        if (tid < FF) s_l[tid] = xb[l * FF + tid];
        __syncthreads();
        if (wave == 0) {
            float z = s_l[lane] / 0.001f;
            float mx = z;
            for (int o = 32; o > 0; o >>= 1) mx = fmaxf(mx, __shfl_xor(mx, o));
            float e = expf(z - mx);
            float sm = e;
            for (int o = 32; o > 0; o >>= 1) sm += __shfl_xor(sm, o);
            float w = e / sm;
            hiW[lane] = w;
            unsigned long long msk = __ballot(w > 1e-16f);
            int pos = (int)__popcll(msk & ((1ull << lane) - 1ull));
            if (w > 1e-16f) JL[pos] = lane;
            if (lane == 0) nIJ[1] = (int)__popcll(msk);
        } else if (wave == 1) {
            float z = 1.0f - s_l[lane] / 0.001f;
            float mx = z;
            for (int o = 32; o > 0; o >>= 1) mx = fmaxf(mx, __shfl_xor(mx, o));
            float e = expf(z - mx);
            float sm = e;
            for (int o = 32; o > 0; o >>= 1) sm += __shfl_xor(sm, o);
            float w = e / sm;
            loW[lane] = w;
            unsigned long long msk = __ballot(w > 1e-16f);
            int pos = (int)__popcll(msk & ((1ull << lane) - 1ull));
            if (w > 1e-16f) IL[pos] = lane;
            if (lane == 0) nIJ[0] = (int)__popcll(msk);
        }
        if (tid < FP1) scoresAcc[tid] = 0.0f;
        __syncthreads();

        const int nI = nIJ[0], nJ = nIJ[1];
        const int npairs = nI * nJ;
        for (int pbase = 0; pbase < npairs; pbase += 8) {
            int prem = npairs - pbase; if (prem > 8) prem = 8;
            int p_local = wave >> 1, half = wave & 1;
            if (p_local < prem) {
                int p = pbase + p_local;
                int i = IL[p / nJ];
                int jx = JL[p % nJ];
                float vv = loW[i] * hiW[jx];
                int k = half * 32 + lane;
                bool act = half ? (lane < 33) : (lane < 32);
                if (act) {
                    const float* base = inter + (size_t)(i * FF + jx) * (FF * FP1) + k;
                    const float* nsv = (k == 0) ? s_l : &Tlds[k - 1][0];
                    float acc = 0.0f;
                    #pragma unroll 16
                    for (int m = 0; m < FF; ++m) acc += base[m * FP1] * nsv[m];
                    chunkA[p_local][k] = vv * acc;
                }
            }
            __syncthreads();
            if (tid < FP1) {
                float a = scoresAcc[tid];
                for (int pl = 0; pl < prem; ++pl) a += chunkA[pl][tid];
                scoresAcc[tid] = a;
            }
            __syncthreads();
        }
        if (tid < FP1) zsc[tid] = scoresAcc[tid] / 0.001f;
        __syncthreads();
        if (tid == 0) {
            float mx = zsc[0];
            for (int k = 1; k < FP1; ++k) mx = fmaxf(mx, zsc[k]);
            redmx = mx;
        }
        __syncthreads();
        if (tid < FP1) zsc[tid] = expf(zsc[tid] - redmx);
        __syncthreads();
        if (tid == 0) {
            float sm = 0.0f;
            for (int k = 0; k < FP1; ++k) sm += zsc[k];
            int cnt = 0;
            for (int k = 0; k < FP1; ++k) {
                float w = zsc[k] / sm;
                swW[k] = w;
                if (w > 1e-14f) { Klist[cnt] = k; Kw[cnt] = w; ++cnt; }
            }
            nK = cnt;
        }
        __syncthreads();

        float ax = 0.f, ay = 0.f, az = 0.f, aw = 0.f;
        const int ij0 = tid * 4;
        for (int kk = 0; kk < nK; ++kk) {
            int k = Klist[kk];
            float wk = Kw[kk];
            float dx = 0.f, dy = 0.f, dz = 0.f, dw = 0.f;
            if (k == 0 && useSlab) {
                const float4* sp = (const float4*)slab0T;
                #pragma unroll 8
                for (int m = 0; m < FF; ++m) {
                    float4 f = sp[m * (FF * FF / 4) + tid];
                    float ns = s_l[m];
                    dx += f.x * ns; dy += f.y * ns; dz += f.z * ns; dw += f.w * ns;
                }
            } else {
                const float* nsv = (k == 0) ? s_l : &Tlds[k - 1][0];
                const float* bp = inter + (size_t)ij0 * (FF * FP1) + k;
                #pragma unroll 8
                for (int m = 0; m < FF; ++m) {
                    float ns = nsv[m];
                    dx += bp[m * FP1] * ns;
                    dy += bp[m * FP1 + FF * FP1] * ns;
                    dz += bp[m * FP1 + 2 * FF * FP1] * ns;
                    dw += bp[m * FP1 + 3 * FF * FP1] * ns;
                }
            }
            ax += wk * dx; ay += wk * dy; az += wk * dz; aw += wk * dw;
        }
        {
            int ii = tid >> 4;
            int jj = (tid & 15) * 4;
            selr[jj + 0][ii] = ax; selr[jj + 1][ii] = ay;
            selr[jj + 2][ii] = az; selr[jj + 3][ii] = aw;
        }
        __syncthreads();
        if (tid < FF) {
            int jcol = tid;
            float mx = -INFINITY;
            for (int i2 = 0; i2 < FF; ++i2) mx = fmaxf(mx, selr[jcol][i2] * 7.0f);
            float sm = 0.0f;
            for (int i2 = 0; i2 < FF; ++i2) {
                float e = expf(selr[jcol][i2] * 7.0f - mx);
                selr[jcol][i2] = e; sm += e;
            }
            for (int i2 = 0; i2 < FF; ++i2) Tlds[jcol][i2] = selr[jcol][i2] / sm;
        }
        __syncthreads();
        if (tid < FF) {
            float acc2 = 0.0f;
            for (int j2 = 0; j2 < FF; ++j2) acc2 += Tlds[j2][tid] * s_l[j2];
            out0[l * FF + tid] = acc2;
        }
    }
    __syncthreads();
    for (int idx = tid; idx < FF * FF; idx += 1024) {
        int i2 = idx >> 6, j2 = idx & 63;
        out1[idx] = Tlds[j2][i2];
    }
}

extern "C" void kernel_launch(void* const* d_in, const int* in_sizes, int n_in,
                              void* d_out, int out_size, void* d_ws, size_t ws_size,
                              hipStream_t stream) {
    const float* x = (const float*)d_in[0];
    const float* inter = (const float*)d_in[1];
    float* outp = (float*)d_out;
    char* ws = (char*)d_ws;

    if (ws_size >= WS_NEED) {
        unsigned short* xH = (unsigned short*)(ws + OFF_XH);
        unsigned short* xL = (unsigned short*)(ws + OFF_XL);
        unsigned short* bH = (unsigned short*)(ws + OFF_BH);
        unsigned short* bL = (unsigned short*)(ws + OFF_BL);
        float* D0 = (float*)(ws + OFF_D0);
        int* flag = (int*)(ws + OFF_FLAG);

        build_slabB<<<dim3(1024), dim3(256), 0, stream>>>(inter, bH, bL);
        build_xA<<<dim3(128), dim3(256), 0, stream>>>(x, xH, xL, flag);
        d0_mfma<<<dim3(32, 32), dim3(256), 0, stream>>>(xH, xL, bH, bL, D0);
        tsm_out<<<dim3(NBL), dim3(256), 0, stream>>>(x, D0, outp, flag);
        // repair: no-op when certificate holds; exact recompute otherwise
        coil_main<<<dim3(BB), dim3(1024), 0, stream>>>(x, inter, (const float*)0, outp, 0, flag);
    } else {
        float* slab0T = (float*)ws;
        int useSlab = (ws_size >= (size_t)FF * FF * FF * sizeof(float)) ? 1 : 0;
        if (useSlab)
            build_slab0<<<dim3(1024), dim3(256), 0, stream>>>(inter, slab0T);
        coil_main<<<dim3(BB), dim3(1024), 0, stream>>>(x, inter, slab0T, outp, useSlab, (const int*)0);
    }
}

// Round 7
// 36.630 us; speedup vs baseline: 11.0463x; 1.2249x over previous
//
#include <hip/hip_runtime.h>
#include <math.h>

#define FF 64
#define FP1 65
#define BB 32
#define LL 128
#define NBL 4096        // BB*LL
#define NIJ 4096        // FF*FF

typedef __attribute__((ext_vector_type(8))) short short8;
typedef __attribute__((ext_vector_type(4))) float f32x4;

__device__ __forceinline__ unsigned short f2b(float f) {   // f32 -> bf16 RNE
    union { float f; unsigned u; } v; v.f = f;
    unsigned r = v.u + 0x7fffu + ((v.u >> 16) & 1u);
    return (unsigned short)(r >> 16);
}
__device__ __forceinline__ float b2f(unsigned short h) {
    union { unsigned u; float f; } v; v.u = ((unsigned)h) << 16; return v.f;
}

// ---- ws layout (bytes) ----
#define OFF_XH   0ull            // xA hi  [2][256][64][8] ushort = 512 KB
#define OFF_XL   524288ull       // xA lo  512 KB
#define OFF_BH   1048576ull      // slabB hi (j-major) 512 KB
#define OFF_BL   1572864ull      // slabB lo 512 KB
#define OFF_FLAG 2097152ull      // 4 B
#define WS_NEED  2097216ull

// ============ stage 1a: slab k=0 slice -> bf16 hi/lo B-fragments, N axis n = j*64+i ============
// t = ((ks*256+fn)*64+lane)*8+e ; n = fn*16+(lane&15); i=n&63; j=n>>6;
// m = ks*32+((lane>>4)&3)*8+e ; value = inter[i][j][m][0]
__global__ void build_slabB(const float* __restrict__ inter,
                            unsigned short* __restrict__ bH,
                            unsigned short* __restrict__ bL) {
    const size_t t = (size_t)blockIdx.x * 256 + threadIdx.x;   // 262144 total
    const int e = (int)(t & 7);
    const int lane = (int)((t >> 3) & 63);
    const int fn = (int)((t >> 9) & 255);
    const int ks = (int)(t >> 17);
    const int n = fn * 16 + (lane & 15);
    const int i = n & 63;
    const int j = n >> 6;
    const int m = ks * 32 + ((lane >> 4) & 3) * 8 + e;
    const float v = inter[((size_t)(i * FF + j) * FF + m) * FP1];
    const unsigned short h = f2b(v);
    bH[t] = h;
    bL[t] = f2b(v - b2f(h));
}

// ============ stage 1b: x -> bf16 hi/lo A-fragments; zero flag ============
__global__ void build_xA(const float* __restrict__ x,
                         unsigned short* __restrict__ xH,
                         unsigned short* __restrict__ xL,
                         int* __restrict__ flag) {
    const int t = blockIdx.x * 256 + threadIdx.x;   // 32768 total
    if (t == 0) *flag = 0;
    const int lane = t & 63;
    const int fm = (t >> 6) & 255;
    const int ks = t >> 14;
    const int bl = fm * 16 + (lane & 15);
    const int fb = ks * 32 + ((lane >> 4) & 3) * 8;
    const float4 v0 = *(const float4*)(x + (size_t)bl * FF + fb);
    const float4 v1 = *(const float4*)(x + (size_t)bl * FF + fb + 4);
    float vv[8] = {v0.x, v0.y, v0.z, v0.w, v1.x, v1.y, v1.z, v1.w};
    unsigned short hh[8], ll[8];
    #pragma unroll
    for (int e = 0; e < 8; ++e) {
        hh[e] = f2b(vv[e]);
        ll[e] = f2b(vv[e] - b2f(hh[e]));
    }
    *(short8*)(xH + (size_t)t * 8) = *(const short8*)hh;
    *(short8*)(xL + (size_t)t * 8) = *(const short8*)ll;
}

// ============ stage 2: fused GEMM (split-bf16 MFMA) + col-softmax + matvec ============
// grid 256 (fm), block 512 = 8 waves; wave w owns j = w*8..w*8+7; block owns 16 bl rows.
// acc frag layout (validated r2/r6): col = lane&15 (i subset), row = (lane>>4)*4+reg (bl subset)
__launch_bounds__(512)
__global__ void fused_mfma(const unsigned short* __restrict__ xH,
                           const unsigned short* __restrict__ xL,
                           const unsigned short* __restrict__ bH,
                           const unsigned short* __restrict__ bL,
                           const float* __restrict__ x,
                           float* __restrict__ out,
                           int* __restrict__ flag) {
    __shared__ float xT[FF][17];        // xT[j][bl_local]
    __shared__ float part[8][FF][17];   // per-wave out partials [i][bl_local]
    __shared__ float wmn[8];

    const int tid = threadIdx.x;
    const int w = tid >> 6, lane = tid & 63;
    const int fm = blockIdx.x;          // 0..255
    const int bl0 = fm * 16;
    const int hi4 = lane >> 4;          // 0..3
    const int c15 = lane & 15;

    for (int idx = tid; idx < 1024; idx += 512) {
        const int bl_local = idx >> 6, j = idx & 63;
        xT[j][bl_local] = x[(size_t)(bl0 + bl_local) * FF + j];
    }
    __syncthreads();

    short8 aH[2], aL[2];
    #pragma unroll
    for (int ks = 0; ks < 2; ++ks) {
        const size_t ab = (((size_t)ks * 256 + fm) * 64 + lane) * 8;
        aH[ks] = *(const short8*)(xH + ab);
        aL[ks] = *(const short8*)(xL + ab);
    }

    f32x4 racc[4];
    #pragma unroll
    for (int q = 0; q < 4; ++q) racc[q] = (f32x4){0.f, 0.f, 0.f, 0.f};
    f32x4 mn4 = (f32x4){INFINITY, INFINITY, INFINITY, INFINITY};

    const bool wrT = ((fm & 7) == 7) && (hi4 == 3);
    float* out1 = out + (size_t)BB * LL * FF + (size_t)(fm >> 3) * NIJ;

    #pragma unroll 1
    for (int jj = 0; jj < 8; ++jj) {
        const int j = w * 8 + jj;
        f32x4 acc[4];
        #pragma unroll
        for (int q = 0; q < 4; ++q) acc[q] = (f32x4){0.f, 0.f, 0.f, 0.f};
        #pragma unroll
        for (int ks = 0; ks < 2; ++ks) {
            #pragma unroll
            for (int q = 0; q < 4; ++q) {
                const size_t bb = (((size_t)ks * 256 + j * 4 + q) * 64 + lane) * 8;
                const short8 bHf = *(const short8*)(bH + bb);
                const short8 bLf = *(const short8*)(bL + bb);
                acc[q] = __builtin_amdgcn_mfma_f32_16x16x32_bf16(aH[ks], bHf, acc[q], 0, 0, 0);
                acc[q] = __builtin_amdgcn_mfma_f32_16x16x32_bf16(aH[ks], bLf, acc[q], 0, 0, 0);
                acc[q] = __builtin_amdgcn_mfma_f32_16x16x32_bf16(aL[ks], bHf, acc[q], 0, 0, 0);
            }
        }
        // z = 7*D0 ; softmax over i = {16 lanes} x {4 frags}
        f32x4 z[4], mxv;
        #pragma unroll
        for (int q = 0; q < 4; ++q) {
            z[q] = acc[q] * 7.0f;
            #pragma unroll
            for (int c = 0; c < 4; ++c) mn4[c] = fminf(mn4[c], z[q][c]);
        }
        #pragma unroll
        for (int c = 0; c < 4; ++c)
            mxv[c] = fmaxf(fmaxf(z[0][c], z[1][c]), fmaxf(z[2][c], z[3][c]));
        #pragma unroll
        for (int o = 1; o < 16; o <<= 1)
            #pragma unroll
            for (int c = 0; c < 4; ++c) mxv[c] = fmaxf(mxv[c], __shfl_xor(mxv[c], o));
        f32x4 e[4], s = (f32x4){0.f, 0.f, 0.f, 0.f};
        #pragma unroll
        for (int q = 0; q < 4; ++q) {
            #pragma unroll
            for (int c = 0; c < 4; ++c) e[q][c] = __expf(z[q][c] - mxv[c]);
            s += e[q];
        }
        #pragma unroll
        for (int o = 1; o < 16; o <<= 1)
            #pragma unroll
            for (int c = 0; c < 4; ++c) s[c] += __shfl_xor(s[c], o);
        f32x4 inv;
        #pragma unroll
        for (int c = 0; c < 4; ++c) inv[c] = 1.0f / s[c];
        f32x4 xbv;
        #pragma unroll
        for (int c = 0; c < 4; ++c) xbv[c] = xT[j][hi4 * 4 + c];
        #pragma unroll
        for (int q = 0; q < 4; ++q) {
            const f32x4 wq = e[q] * inv;
            racc[q] += wq * xbv;
            if (wrT) out1[(q * 16 + c15) * 64 + j] = wq[3];   // bl_local 15 -> l=127
        }
    }

    #pragma unroll
    for (int q = 0; q < 4; ++q)
        #pragma unroll
        for (int r = 0; r < 4; ++r)
            part[w][q * 16 + c15][hi4 * 4 + r] = racc[q][r];

    float mn = fminf(fminf(mn4[0], mn4[1]), fminf(mn4[2], mn4[3]));
    #pragma unroll
    for (int o = 1; o < 64; o <<= 1) mn = fminf(mn, __shfl_xor(mn, o));
    if (lane == 0) wmn[w] = mn;
    __syncthreads();

    for (int idx = tid; idx < 1024; idx += 512) {
        const int bl_local = idx >> 6, i = idx & 63;
        float a = 0.f;
        #pragma unroll
        for (int ww = 0; ww < 8; ++ww) a += part[ww][i][bl_local];
        out[(size_t)(bl0 + bl_local) * FF + i] = a;
    }
    if (tid == 0) {
        float m2 = wmn[0];
        #pragma unroll
        for (int ww = 1; ww < 8; ++ww) m2 = fminf(m2, wmn[ww]);
        if (!(m2 >= 10.5f)) atomicOr(flag, 1);   // also catches NaN
    }
}

// ============ fallback slab build (small-ws path only) ============
__global__ void build_slab0(const float* __restrict__ inter, float* __restrict__ slab0T) {
    int t = blockIdx.x * blockDim.x + threadIdx.x;
    if (t < FF * FF * FF) {
        int m = t >> 12;
        int ij = t & 4095;
        slab0T[t] = inter[((size_t)ij * FF + m) * FP1];
    }
}

// ==================== exact sequential fallback / repair (verified round-1) ====================
__launch_bounds__(1024, 1)
__global__ void coil_main(const float* __restrict__ x,
                          const float* __restrict__ inter,
                          const float* __restrict__ slab0T,
                          float* __restrict__ out,
                          int useSlab,
                          const int* __restrict__ flag) {
    if (flag && *flag == 0) return;   // certificate held: parallel path already correct

    __shared__ float Tlds[FF][FP1];
    __shared__ float selr[FF][FP1];
    __shared__ float s_l[FF], hiW[FF], loW[FF];
    __shared__ float zsc[FP1], swW[FP1], scoresAcc[FP1];
    __shared__ float chunkA[8][FP1 + 3];
    __shared__ int IL[FF], JL[FF];
    __shared__ int nIJ[2];
    __shared__ int Klist[FP1];
    __shared__ float Kw[FP1];
    __shared__ int nK;
    __shared__ float redmx;

    const int b = blockIdx.x;
    const int tid = threadIdx.x;
    const int wave = tid >> 6;
    const int lane = tid & 63;

    for (int idx = tid; idx < FF * FP1; idx += 1024)
        ((float*)Tlds)[idx] = 1.0f / FF;

    const float* xb = x + (size_t)b * LL * FF;
    float* out0 = out + (size_t)b * LL * FF;
    float* out1 = out + (size_t)BB * LL * FF + (size_t)b * FF * FF;

    for (int l = 0; l < LL; ++l) {
        __syncthreads();
        if (tid < FF) s_l[tid] = xb[l * FF + tid];
        __syncthreads();
        if (wave == 0) {
            float z = s_l[lane] / 0.001f;
            float mx = z;
            for (int o = 32; o > 0; o >>= 1) mx = fmaxf(mx, __shfl_xor(mx, o));
            float e = expf(z - mx);
            float sm = e;
            for (int o = 32; o > 0; o >>= 1) sm += __shfl_xor(sm, o);
            float w = e / sm;
            hiW[lane] = w;
            unsigned long long msk = __ballot(w > 1e-16f);
            int pos = (int)__popcll(msk & ((1ull << lane) - 1ull));
            if (w > 1e-16f) JL[pos] = lane;
            if (lane == 0) nIJ[1] = (int)__popcll(msk);
        } else if (wave == 1) {
            float z = 1.0f - s_l[lane] / 0.001f;
            float mx = z;
            for (int o = 32; o > 0; o >>= 1) mx = fmaxf(mx, __shfl_xor(mx, o));
            float e = expf(z - mx);
            float sm = e;
            for (int o = 32; o > 0; o >>= 1) sm += __shfl_xor(sm, o);
            float w = e / sm;
            loW[lane] = w;
            unsigned long long msk = __ballot(w > 1e-16f);
            int pos = (int)__popcll(msk & ((1ull << lane) - 1ull));
            if (w > 1e-16f) IL[pos] = lane;
            if (lane == 0) nIJ[0] = (int)__popcll(msk);
        }
        if (tid < FP1) scoresAcc[tid] = 0.0f;
        __syncthreads();

        const int nI = nIJ[0], nJ = nIJ[1];
        const int npairs = nI * nJ;
        for (int pbase = 0; pbase < npairs; pbase += 8) {
            int prem = npairs - pbase; if (prem > 8) prem = 8;
            int p_local = wave >> 1, half = wave & 1;
            if (p_local < prem) {
                int p = pbase + p_local;
                int i = IL[p / nJ];
                int jx = JL[p % nJ];
                float vv = loW[i] * hiW[jx];
                int k = half * 32 + lane;
                bool act = half ? (lane < 33) : (lane < 32);
                if (act) {
                    const float* base = inter + (size_t)(i * FF + jx) * (FF * FP1) + k;
                    const float* nsv = (k == 0) ? s_l : &Tlds[k - 1][0];
                    float acc = 0.0f;
                    #pragma unroll 16
                    for (int m = 0; m < FF; ++m) acc += base[m * FP1] * nsv[m];
                    chunkA[p_local][k] = vv * acc;
                }
            }
            __syncthreads();
            if (tid < FP1) {
                float a = scoresAcc[tid];
                for (int pl = 0; pl < prem; ++pl) a += chunkA[pl][tid];
                scoresAcc[tid] = a;
            }
            __syncthreads();
        }
        if (tid < FP1) zsc[tid] = scoresAcc[tid] / 0.001f;
        __syncthreads();
        if (tid == 0) {
            float mx = zsc[0];
            for (int k = 1; k < FP1; ++k) mx = fmaxf(mx, zsc[k]);
            redmx = mx;
        }
        __syncthreads();
        if (tid < FP1) zsc[tid] = expf(zsc[tid] - redmx);
        __syncthreads();
        if (tid == 0) {
            float sm = 0.0f;
            for (int k = 0; k < FP1; ++k) sm += zsc[k];
            int cnt = 0;
            for (int k = 0; k < FP1; ++k) {
                float w = zsc[k] / sm;
                swW[k] = w;
                if (w > 1e-14f) { Klist[cnt] = k; Kw[cnt] = w; ++cnt; }
            }
            nK = cnt;
        }
        __syncthreads();

        float ax = 0.f, ay = 0.f, az = 0.f, aw = 0.f;
        const int ij0 = tid * 4;
        for (int kk = 0; kk < nK; ++kk) {
            int k = Klist[kk];
            float wk = Kw[kk];
            float dx = 0.f, dy = 0.f, dz = 0.f, dw = 0.f;
            if (k == 0 && useSlab) {
                const float4* sp = (const float4*)slab0T;
                #pragma unroll 8
                for (int m = 0; m < FF; ++m) {
                    float4 f = sp[m * (FF * FF / 4) + tid];
                    float ns = s_l[m];
                    dx += f.x * ns; dy += f.y * ns; dz += f.z * ns; dw += f.w * ns;
                }
            } else {
                const float* nsv = (k == 0) ? s_l : &Tlds[k - 1][0];
                const float* bp = inter + (size_t)ij0 * (FF * FP1) + k;
                #pragma unroll 8
                for (int m = 0; m < FF; ++m) {
                    float ns = nsv[m];
                    dx += bp[m * FP1] * ns;
                    dy += bp[m * FP1 + FF * FP1] * ns;
                    dz += bp[m * FP1 + 2 * FF * FP1] * ns;
                    dw += bp[m * FP1 + 3 * FF * FP1] * ns;
                }
            }
            ax += wk * dx; ay += wk * dy; az += wk * dz; aw += wk * dw;
        }
        {
            int ii = tid >> 4;
            int jj = (tid & 15) * 4;
            selr[jj + 0][ii] = ax; selr[jj + 1][ii] = ay;
            selr[jj + 2][ii] = az; selr[jj + 3][ii] = aw;
        }
        __syncthreads();
        if (tid < FF) {
            int jcol = tid;
            float mx = -INFINITY;
            for (int i2 = 0; i2 < FF; ++i2) mx = fmaxf(mx, selr[jcol][i2] * 7.0f);
            float sm = 0.0f;
            for (int i2 = 0; i2 < FF; ++i2) {
                float e = expf(selr[jcol][i2] * 7.0f - mx);
                selr[jcol][i2] = e; sm += e;
            }
            for (int i2 = 0; i2 < FF; ++i2) Tlds[jcol][i2] = selr[jcol][i2] / sm;
        }
        __syncthreads();
        if (tid < FF) {
            float acc2 = 0.0f;
            for (int j2 = 0; j2 < FF; ++j2) acc2 += Tlds[j2][tid] * s_l[j2];
            out0[l * FF + tid] = acc2;
        }
    }
    __syncthreads();
    for (int idx = tid; idx < FF * FF; idx += 1024) {
        int i2 = idx >> 6, j2 = idx & 63;
        out1[idx] = Tlds[j2][i2];
    }
}

extern "C" void kernel_launch(void* const* d_in, const int* in_sizes, int n_in,
                              void* d_out, int out_size, void* d_ws, size_t ws_size,
                              hipStream_t stream) {
    const float* x = (const float*)d_in[0];
    const float* inter = (const float*)d_in[1];
    float* outp = (float*)d_out;
    char* ws = (char*)d_ws;

    if (ws_size >= WS_NEED) {
        unsigned short* xH = (unsigned short*)(ws + OFF_XH);
        unsigned short* xL = (unsigned short*)(ws + OFF_XL);
        unsigned short* bH = (unsigned short*)(ws + OFF_BH);
        unsigned short* bL = (unsigned short*)(ws + OFF_BL);
        int* flag = (int*)(ws + OFF_FLAG);

        build_slabB<<<dim3(1024), dim3(256), 0, stream>>>(inter, bH, bL);
        build_xA<<<dim3(128), dim3(256), 0, stream>>>(x, xH, xL, flag);
        fused_mfma<<<dim3(256), dim3(512), 0, stream>>>(xH, xL, bH, bL, x, outp, flag);
        // repair: no-op when certificate holds; exact recompute otherwise
        coil_main<<<dim3(BB), dim3(1024), 0, stream>>>(x, inter, (const float*)0, outp, 0, flag);
    } else {
        float* slab0T = (float*)ws;
        int useSlab = (ws_size >= (size_t)FF * FF * FF * sizeof(float)) ? 1 : 0;
        if (useSlab)
            build_slab0<<<dim3(1024), dim3(256), 0, stream>>>(inter, slab0T);
        coil_main<<<dim3(BB), dim3(1024), 0, stream>>>(x, inter, slab0T, outp, useSlab, (const int*)0);
    }
}